// Round 3
// baseline (224.169 us; speedup 1.0000x reference)
//
#include <hip/hip_runtime.h>

// out[b,o,n] = max_d |x[b,d,n] - w[o,d]| + bias[o]
// B=64, CIN=1024, COUT=1024, N=49. Pixels P = B*N = 3136 = 49*64.
//
// Round-3: same structure as round-2 (lane=pixel, 8 ch/wave, w scalarized to
// s_load, no LDS), but force the minimal inner-loop instruction mix:
//   - subs as <2 x float> hoping for v_pk_add_f32 neg_lo/neg_hi (1 instr / 2 subs)
//   - max+abs forced to a single v_max3_f32 acc, acc, |d0|, |d1| via inline asm
// Round-2 counters showed ~3.2 VALU instr/update (compiler emitted and/max
// instead of fused max3-with-abs). Target: 1.0-1.5 instr/update.

typedef float v2f __attribute__((ext_vector_type(2)));

constexpr int CIN  = 1024;
constexpr int COUT = 1024;
constexpr int NN   = 49;
constexpr int BB   = 64;
constexpr int P    = BB * NN;   // 3136
constexpr int CPW  = 8;         // channels per wave
constexpr int WPB  = 4;         // waves per block
constexpr int CPB  = CPW * WPB; // 32 channels per block
constexpr int KU   = 8;         // k unroll

__global__ __launch_bounds__(256) void ndist_kernel(
    const float* __restrict__ x, const float* __restrict__ w,
    const float* __restrict__ bias, float* __restrict__ out)
{
    const int lane = threadIdx.x & 63;
    const int wid  = __builtin_amdgcn_readfirstlane(threadIdx.x >> 6);

    const int p = blockIdx.x * BB + lane;    // pixel (3136 = 49*64, exact)
    const int b = p / NN;
    const int n = p - b * NN;
    const int o0 = blockIdx.y * CPB + wid * CPW;

    const float* __restrict__ xrow = x + (size_t)b * CIN * NN + n;

    float acc[CPW];
#pragma unroll
    for (int c = 0; c < CPW; ++c) acc[c] = 0.0f;   // |diff| >= 0, identity ok

    for (int k0 = 0; k0 < CIN; k0 += KU) {
        // 8 coalesced dword loads (immediate offsets off one advancing base)
        float xv[KU];
#pragma unroll
        for (int j = 0; j < KU; ++j) xv[j] = xrow[(k0 + j) * NN];

#pragma unroll
        for (int c = 0; c < CPW; ++c) {
            const float* __restrict__ wr = w + (size_t)(o0 + c) * CIN + k0;  // uniform -> s_load
#pragma unroll
            for (int j = 0; j < KU; j += 2) {
                v2f xp = { xv[j], xv[j + 1] };
                v2f wp = { wr[j], wr[j + 1] };          // SGPR pair
                v2f d  = xp - wp;                       // hope: v_pk_add_f32 neg:[0,1]
                // guaranteed single instr for abs+abs+max+max:
                asm("v_max3_f32 %0, %0, |%1|, |%2|"
                    : "+v"(acc[c]) : "v"(d.x), "v"(d.y));
            }
        }
    }

#pragma unroll
    for (int c = 0; c < CPW; ++c) {
        const int o = o0 + c;
        out[((size_t)b * COUT + o) * NN + n] = acc[c] + bias[o];
    }
}

extern "C" void kernel_launch(void* const* d_in, const int* in_sizes, int n_in,
                              void* d_out, int out_size, void* d_ws, size_t ws_size,
                              hipStream_t stream) {
    const float* x    = (const float*)d_in[0];
    const float* w    = (const float*)d_in[1];
    const float* bias = (const float*)d_in[2];
    float* out        = (float*)d_out;

    dim3 grid(P / BB, COUT / CPB);  // 49 x 32 = 1568 blocks
    ndist_kernel<<<grid, 256, 0, stream>>>(x, w, bias, out);
}

// Round 4
// 157.965 us; speedup vs baseline: 1.4191x; 1.4191x over previous
//
#include <hip/hip_runtime.h>

// out[b,o,n] = max_d |x[b,d,n] - w[o,d]| + bias[o]
// B=64, CIN=1024, COUT=1024, N=49. Pixels P = B*N = 3136 = 49*64.
//
// Round-4: keep round-2 structure (lane=pixel, 8 ch/wave, 4 waves/block, no LDS,
// no barriers), force minimal VALU mix:
//   per 4 updates (2 k x 2 ch): 2x v_pk_add_f32 (SGPR-pair w, neg-modified x)
//                             + 2x v_max3_f32 acc,acc,|d0|,|d1|   => 1.0 instr/update
// w is pre-packed into wQ[kt][og][ku][oc] so each (wave, k-tile) reads 32
// CONTIGUOUS floats (2x s_load_dwordx16) and channel pairs are SGPR-pair-adjacent.
// x is double-buffered one k-tile ahead in program order (round-3 lesson: asm
// blocks the scheduler's own hoisting, so prefetch explicitly).

typedef float v2f __attribute__((ext_vector_type(2)));

constexpr int CIN  = 1024;
constexpr int COUT = 1024;
constexpr int NN   = 49;
constexpr int BB   = 64;
constexpr int P    = BB * NN;        // 3136
constexpr int CPW  = 8;              // channels per wave
constexpr int WPB  = 4;              // waves per block
constexpr int CPB  = CPW * WPB;      // 32 channels per block
constexpr int KU   = 4;              // k per tile
constexpr int NKT  = CIN / KU;       // 256 k-tiles

// Pack: wq[(((kt*(COUT/8) + og)*KU + ku)*8 + oc)] = w[o][k], o=og*8+oc, k=kt*4+ku
__global__ void pack_w_kernel(const float* __restrict__ w, float* __restrict__ wq) {
    int idx = blockIdx.x * 256 + threadIdx.x;       // COUT*CIN = 4096*256 exact
    int o = idx >> 10, k = idx & 1023;
    int kt = k >> 2, ku = k & 3, og = o >> 3, oc = o & 7;
    wq[(((size_t)kt * (COUT / 8) + og) * KU + ku) * 8 + oc] = w[idx];
}

__device__ __forceinline__ void compute4(const float (&xv)[KU],
                                         const v2f* __restrict__ wrow,
                                         float (&acc)[CPW]) {
    v2f wv[16];                       // 32 floats: [ku][oc], uniform -> s_load_dwordx16 x2
#pragma unroll
    for (int q = 0; q < 16; ++q) wv[q] = wrow[q];
#pragma unroll
    for (int k = 0; k < KU; k += 2) {
        v2f xx0 = { xv[k],     xv[k]     };
        v2f xx1 = { xv[k + 1], xv[k + 1] };
#pragma unroll
        for (int cp = 0; cp < 4; ++cp) {
            v2f d0, d1;
            asm("v_pk_add_f32 %0, %1, %2 neg_lo:[0,1] neg_hi:[0,1]"
                : "=v"(d0) : "s"(wv[k * 4 + cp]), "v"(xx0));
            asm("v_pk_add_f32 %0, %1, %2 neg_lo:[0,1] neg_hi:[0,1]"
                : "=v"(d1) : "s"(wv[(k + 1) * 4 + cp]), "v"(xx1));
            asm("v_max3_f32 %0, %0, |%1|, |%2|"
                : "+v"(acc[2 * cp])     : "v"(d0.x), "v"(d1.x));
            asm("v_max3_f32 %0, %0, |%1|, |%2|"
                : "+v"(acc[2 * cp + 1]) : "v"(d0.y), "v"(d1.y));
        }
    }
}

__global__ __launch_bounds__(256) void ndist_kernel(
    const float* __restrict__ x, const float* __restrict__ wq,
    const float* __restrict__ bias, float* __restrict__ out)
{
    const int lane = threadIdx.x & 63;
    const int wid  = __builtin_amdgcn_readfirstlane(threadIdx.x >> 6);

    const int p = blockIdx.x * BB + lane;          // pixel (exact: 3136=49*64)
    const int b = p / NN;
    const int n = p - b * NN;
    const int og = blockIdx.y * WPB + wid;         // 8-channel group id
    const int o0 = og * CPW;

    const float* __restrict__ xrow  = x + (size_t)b * CIN * NN + n;
    const v2f*   __restrict__ wbase = (const v2f*)(wq + (size_t)og * 32);
    constexpr size_t WKT = (size_t)(COUT / 8) * 16;  // v2f stride per k-tile (=2048)

    float acc[CPW];
#pragma unroll
    for (int c = 0; c < CPW; ++c) acc[c] = 0.0f;   // |diff| >= 0

    float xa[KU], xb[KU];
#pragma unroll
    for (int j = 0; j < KU; ++j) xa[j] = xrow[j * NN];   // k-tile 0

    for (int kt = 0; kt < NKT; kt += 2) {
        // prefetch x for kt+1 (always valid: NKT even)
#pragma unroll
        for (int j = 0; j < KU; ++j) xb[j] = xrow[((kt + 1) * KU + j) * NN];
        compute4(xa, wbase + (size_t)kt * WKT, acc);

        // prefetch x for kt+2 (clamped; redundant reload on last iter is harmless)
        const int ktn = (kt + 2 < NKT) ? kt + 2 : 0;
#pragma unroll
        for (int j = 0; j < KU; ++j) xa[j] = xrow[(ktn * KU + j) * NN];
        compute4(xb, wbase + (size_t)(kt + 1) * WKT, acc);
    }

#pragma unroll
    for (int c = 0; c < CPW; ++c) {
        const int o = o0 + c;
        out[((size_t)b * COUT + o) * NN + n] = acc[c] + bias[o];  // bias: s_load
    }
}

// ---- fallback (round-2 kernel, used only if ws too small for packed w) ----
__global__ __launch_bounds__(256) void ndist_fallback(
    const float* __restrict__ x, const float* __restrict__ w,
    const float* __restrict__ bias, float* __restrict__ out)
{
    const int lane = threadIdx.x & 63;
    const int wid  = __builtin_amdgcn_readfirstlane(threadIdx.x >> 6);
    const int p = blockIdx.x * BB + lane;
    const int b = p / NN, n = p - b * NN;
    const int o0 = blockIdx.y * CPB + wid * CPW;
    const float* __restrict__ xrow = x + (size_t)b * CIN * NN + n;

    float acc[CPW];
#pragma unroll
    for (int c = 0; c < CPW; ++c) acc[c] = 0.0f;

    for (int k0 = 0; k0 < CIN; k0 += 8) {
        float xv[8];
#pragma unroll
        for (int j = 0; j < 8; ++j) xv[j] = xrow[(k0 + j) * NN];
#pragma unroll
        for (int c = 0; c < CPW; ++c) {
            const float* __restrict__ wr = w + (size_t)(o0 + c) * CIN + k0;
#pragma unroll
            for (int j = 0; j < 8; j += 2) {
                float d0 = xv[j] - wr[j];
                float d1 = xv[j + 1] - wr[j + 1];
                acc[c] = fmaxf(fmaxf(acc[c], __builtin_fabsf(d0)),
                               __builtin_fabsf(d1));
            }
        }
    }
#pragma unroll
    for (int c = 0; c < CPW; ++c) {
        const int o = o0 + c;
        out[((size_t)b * COUT + o) * NN + n] = acc[c] + bias[o];
    }
}

extern "C" void kernel_launch(void* const* d_in, const int* in_sizes, int n_in,
                              void* d_out, int out_size, void* d_ws, size_t ws_size,
                              hipStream_t stream) {
    const float* x    = (const float*)d_in[0];
    const float* w    = (const float*)d_in[1];
    const float* bias = (const float*)d_in[2];
    float* out        = (float*)d_out;

    const size_t wq_bytes = (size_t)COUT * CIN * sizeof(float);  // 4 MB
    if (ws_size >= wq_bytes) {
        float* wq = (float*)d_ws;
        pack_w_kernel<<<(COUT * CIN) / 256, 256, 0, stream>>>(w, wq);
        dim3 grid(P / BB, COUT / CPB);   // 49 x 32
        ndist_kernel<<<grid, 256, 0, stream>>>(x, wq, bias, out);
    } else {
        dim3 grid(P / BB, COUT / CPB);
        ndist_fallback<<<grid, 256, 0, stream>>>(x, w, bias, out);
    }
}

// Round 5
// 136.179 us; speedup vs baseline: 1.6461x; 1.1600x over previous
//
#include <hip/hip_runtime.h>

// out[b,o,n] = max_d |x[b,d,n] - w[o,d]| + bias[o]
// B=64, CIN=1024, COUT=1024, N=49. Pixels P = B*N = 3136 = 49*64.
//
// Round-5: lane=pixel, 8 ch/wave, 4 waves/block, no LDS/barriers.
// Inner mix per (channel, k-pair):   d = v_pk_add_f32(w_pair[SGPR], -x_pair[VGPR])
//                                    v_max3_f32 acc, acc, |d.x|, |d.y|
// => 1.0 VALU instr/update, no broadcast movs (k-pair packs the VGPR pair).
// w stays in its native layout (k-contiguous) -> s_load_dwordx4 per channel with
// immediate offsets; double-buffered in SGPRs. x double-buffered in VGPRs.
// Grid = (og=32, pix=49): consecutive blocks share the x tile (L2 locality).

typedef float v2f __attribute__((ext_vector_type(2)));
typedef float v4f __attribute__((ext_vector_type(4)));

constexpr int CIN  = 1024;
constexpr int COUT = 1024;
constexpr int NN   = 49;
constexpr int BB   = 64;
constexpr int P    = BB * NN;     // 3136
constexpr int CPW  = 8;           // channels per wave
constexpr int WPB  = 4;           // waves per block
constexpr int CPB  = CPW * WPB;   // 32 channels per block
constexpr int NT   = CIN / 4;     // 256 k-tiles of 4

#define PKSUB(d, wp, xp) \
    asm("v_pk_add_f32 %0, %1, %2 neg_lo:[0,1] neg_hi:[0,1]" \
        : "=v"(d) : "s"(wp), "v"(xp))
#define AMAX3(a, lo, hi) \
    asm("v_max3_f32 %0, %0, |%1|, |%2|" : "+v"(a) : "v"(lo), "v"(hi))

__global__ __launch_bounds__(256) void ndist_kernel(
    const float* __restrict__ x, const float* __restrict__ w,
    const float* __restrict__ bias, float* __restrict__ out)
{
    const int lane = threadIdx.x & 63;
    const int wid  = __builtin_amdgcn_readfirstlane(threadIdx.x >> 6);

    const int p = blockIdx.y * BB + lane;     // pixel (exact: 3136 = 49*64)
    const int b = p / NN;
    const int n = p - b * NN;
    const int o0 = blockIdx.x * CPB + wid * CPW;

    const float* __restrict__ xrow = x + (size_t)b * CIN * NN + n;
    const float* __restrict__ wb   = w + (size_t)o0 * CIN;   // wave-uniform base

    float acc[CPW];
#pragma unroll
    for (int c = 0; c < CPW; ++c) acc[c] = 0.0f;   // |diff| >= 0

    // --- double buffers ---
    v2f xA[2], xB[2];          // x k-pairs (VGPR pairs)
    v2f wA[CPW][2], wB[CPW][2];// w k-pairs (SGPR pairs via s_load_dwordx4)

#define LOAD_X(dst, kt) do {                                   \
        float _x0 = xrow[((kt) * 4 + 0) * NN];                 \
        float _x1 = xrow[((kt) * 4 + 1) * NN];                 \
        float _x2 = xrow[((kt) * 4 + 2) * NN];                 \
        float _x3 = xrow[((kt) * 4 + 3) * NN];                 \
        dst[0] = (v2f){_x0, _x1};                              \
        dst[1] = (v2f){_x2, _x3};                              \
    } while (0)

#define LOAD_W(dst, kt) do {                                   \
        _Pragma("unroll")                                      \
        for (int c = 0; c < CPW; ++c) {                        \
            v4f t = *(const v4f*)(wb + (size_t)c * CIN + (kt) * 4); \
            dst[c][0] = (v2f){t.x, t.y};                       \
            dst[c][1] = (v2f){t.z, t.w};                       \
        }                                                      \
    } while (0)

#define COMPUTE(xv, wv) do {                                   \
        _Pragma("unroll")                                      \
        for (int c = 0; c < CPW; ++c) {                        \
            v2f d0, d1;                                        \
            PKSUB(d0, wv[c][0], xv[0]);                        \
            PKSUB(d1, wv[c][1], xv[1]);                        \
            AMAX3(acc[c], d0.x, d0.y);                         \
            AMAX3(acc[c], d1.x, d1.y);                         \
        }                                                      \
    } while (0)

    LOAD_X(xA, 0);
    LOAD_W(wA, 0);

    for (int kt = 0; kt < NT; kt += 2) {
        // prefetch tile kt+1, compute tile kt
        LOAD_X(xB, kt + 1);
        LOAD_W(wB, kt + 1);
        COMPUTE(xA, wA);

        // prefetch tile kt+2 (wrap on last iter; harmless redundant load)
        const int ktn = (kt + 2) & (NT - 1);
        LOAD_X(xA, ktn);
        LOAD_W(wA, ktn);
        COMPUTE(xB, wB);
    }

#pragma unroll
    for (int c = 0; c < CPW; ++c) {
        const int o = o0 + c;
        out[((size_t)b * COUT + o) * NN + n] = acc[c] + bias[o];  // bias: s_load
    }
}

extern "C" void kernel_launch(void* const* d_in, const int* in_sizes, int n_in,
                              void* d_out, int out_size, void* d_ws, size_t ws_size,
                              hipStream_t stream) {
    const float* x    = (const float*)d_in[0];
    const float* w    = (const float*)d_in[1];
    const float* bias = (const float*)d_in[2];
    float* out        = (float*)d_out;

    dim3 grid(COUT / CPB, P / BB);   // (32 channel-groups, 49 pixel-tiles)
    ndist_kernel<<<grid, 256, 0, stream>>>(x, w, bias, out);
}